// Round 2
// baseline (122.021 us; speedup 1.0000x reference)
//
#include <hip/hip_runtime.h>

// Fixed problem geometry from setup_inputs(): X (32,512,512,8) f32, theta (32,6) f32
constexpr int B = 32;
constexpr int H = 512;
constexpr int W = 512;
constexpr int HW = H * W;          // 262144 = 2^18

// One thread per (output pixel, channel-half). half=idx&1 selects channels [0..3] or [4..7].
// Consecutive lanes -> consecutive float4 writes (fully coalesced).
//
// Coordinate math is done in DOUBLE precision replicating numpy-f64 semantics:
// the sampling function is discontinuous at the clip borders (x=0, x=W-1, y=0,
// y=H-1), so f32 coordinate math flips floor/clip decisions vs the numpy f64
// reference and produces O(|X|) errors there (round-1: absmax 0.094 > 0.0875).
__global__ __launch_bounds__(256) void stn_bilinear_kernel(
    const float4* __restrict__ X4,     // X viewed as float4: 2 per pixel
    const float*  __restrict__ theta,  // (B,6)
    float4*       __restrict__ out4)   // same layout as X4
{
    const int idx  = blockIdx.x * 256 + threadIdx.x;  // 0 .. B*HW*2-1, exact grid
    const int half = idx & 1;
    const int pix  = idx >> 1;
    const int b    = pix >> 18;          // / HW
    const int p    = pix & (HW - 1);
    const int h    = p >> 9;             // / W
    const int w    = p & (W - 1);

    // theta is wave-uniform (a 256-thread block spans 128 pixels of one image)
    const float* t = theta + b * 6;
    const double t0 = (double)t[0], t1 = (double)t[1], t2 = (double)t[2];
    const double t3 = (double)t[3], t4 = (double)t[4], t5 = (double)t[5];

    // numpy linspace(-1,1,512) f64: i*delta + start, endpoint forced to stop
    const double step = 2.0 / 511.0;
    const double xg = (w == W - 1) ? 1.0 : (double)w * step - 1.0;
    const double yg = (h == H - 1) ? 1.0 : (double)h * step - 1.0;

    // einsum('bij,jn->bin'): t0*xg + t1*yg + t2, evaluated in f64
    const double xt = (t0 * xg + t1 * yg) + t2;
    const double yt = (t3 * xg + t4 * yg) + t5;

    // x = 0.5 * (x + 1.0) * float32(W)  -> ((0.5*(x+1.0)) * 512.0) in f64
    const double x = (0.5 * (xt + 1.0)) * (double)W;
    const double y = (0.5 * (yt + 1.0)) * (double)H;

    const double xf = floor(x);
    const double yf = floor(y);
    int x0 = (int)xf;
    int y0 = (int)yf;
    int x1 = x0 + 1;
    int y1 = y0 + 1;
    x0 = min(max(x0, 0), W - 1);
    x1 = min(max(x1, 0), W - 1);
    y0 = min(max(y0, 0), H - 1);
    y1 = min(max(y1, 0), H - 1);

    // Weights from the CLIPPED coords (matches the reference exactly)
    const double x0f = (double)x0, x1f = (double)x1;
    const double y0f = (double)y0, y1f = (double)y1;
    const double wa = (x1f - x) * (y1f - y);
    const double wb = (x1f - x) * (y - y0f);
    const double wc = (x - x0f) * (y1f - y);
    const double wd = (x - x0f) * (y - y0f);

    const int base = b << 18;
    const int ia = (((base | (y0 << 9)) | x0) << 1) + half;
    const int ib = (((base | (y1 << 9)) | x0) << 1) + half;
    const int ic = (((base | (y0 << 9)) | x1) << 1) + half;
    const int id = (((base | (y1 << 9)) | x1) << 1) + half;

    const float4 A  = X4[ia];
    const float4 Bv = X4[ib];
    const float4 Cv = X4[ic];
    const float4 Dv = X4[id];

    // Blend in f64, left-to-right like the numpy expression, then round once.
    float4 o;
    o.x = (float)(((wa * (double)A.x + wb * (double)Bv.x) + wc * (double)Cv.x) + wd * (double)Dv.x);
    o.y = (float)(((wa * (double)A.y + wb * (double)Bv.y) + wc * (double)Cv.y) + wd * (double)Dv.y);
    o.z = (float)(((wa * (double)A.z + wb * (double)Bv.z) + wc * (double)Cv.z) + wd * (double)Dv.z);
    o.w = (float)(((wa * (double)A.w + wb * (double)Bv.w) + wc * (double)Cv.w) + wd * (double)Dv.w);

    out4[idx] = o;
}

extern "C" void kernel_launch(void* const* d_in, const int* in_sizes, int n_in,
                              void* d_out, int out_size, void* d_ws, size_t ws_size,
                              hipStream_t stream) {
    const float4* X4    = (const float4*)d_in[0];
    const float*  theta = (const float*)d_in[1];
    float4*       out4  = (float4*)d_out;

    const int total_threads = B * HW * 2;           // 16,777,216
    const int blocks = total_threads / 256;         // 65536, exact

    stn_bilinear_kernel<<<blocks, 256, 0, stream>>>(X4, theta, out4);
}

// Round 4
// 107.276 us; speedup vs baseline: 1.1374x; 1.1374x over previous
//
#include <hip/hip_runtime.h>

// Fixed problem geometry from setup_inputs(): X (32,512,512,8) f32, theta (32,6) f32
constexpr int B = 32;
constexpr int H = 512;
constexpr int W = 512;
constexpr int HW = H * W;          // 262144 = 2^18
constexpr int NXCD = 8;

// Native vector type: __builtin_nontemporal_store requires scalar/ext-vector,
// not HIP_vector_type<float,4>.
typedef float f32x4 __attribute__((ext_vector_type(4)));

// One thread per output PIXEL (8 channels = 2 float4). Coordinate math (f64,
// numpy-exact: border discontinuities at x=0/W-1, y=0/H-1 need f64 to match the
// numpy reference's floor/clip decisions) is done ONCE per pixel. Each thread
// gathers 4 corners x 2 float4 = 8 loads (good MLP), writes 2 nontemporal
// float4 stores (output is write-once -> keep L2/L3 for the gather reuse).
__global__ __launch_bounds__(256) void stn_bilinear_kernel(
    const f32x4* __restrict__ X4,      // X viewed as f32x4: 2 per pixel
    const float* __restrict__ theta,   // (B,6)
    f32x4*       __restrict__ out4)    // same layout as X4
{
    // XCD-aware bijective swizzle: 32768 blocks, 8 XCDs -> contiguous chunks
    // of 4096 blocks per XCD (keeps an image's source rows in one L2).
    const int nblk = (B * HW) / 256;               // 32768
    const int cpx  = nblk / NXCD;                  // 4096
    const int bid  = (int)blockIdx.x;
    const int swz  = (bid % NXCD) * cpx + bid / NXCD;

    const int idx = swz * 256 + (int)threadIdx.x;  // 0 .. B*HW-1, exact
    const int b   = idx >> 18;                     // / HW
    const int p   = idx & (HW - 1);
    const int h   = p >> 9;                        // / W
    const int w   = p & (W - 1);

    const float* t = theta + b * 6;                // wave-uniform
    const double t0 = (double)t[0], t1 = (double)t[1], t2 = (double)t[2];
    const double t3 = (double)t[3], t4 = (double)t[4], t5 = (double)t[5];

    // numpy linspace(-1,1,512) f64: i*delta + start, endpoint forced to stop
    const double step = 2.0 / 511.0;
    const double xg = (w == W - 1) ? 1.0 : (double)w * step - 1.0;
    const double yg = (h == H - 1) ? 1.0 : (double)h * step - 1.0;

    const double xt = (t0 * xg + t1 * yg) + t2;
    const double yt = (t3 * xg + t4 * yg) + t5;

    const double x = (0.5 * (xt + 1.0)) * (double)W;
    const double y = (0.5 * (yt + 1.0)) * (double)H;

    int x0 = (int)floor(x);
    int y0 = (int)floor(y);
    int x1 = x0 + 1;
    int y1 = y0 + 1;
    x0 = min(max(x0, 0), W - 1);
    x1 = min(max(x1, 0), W - 1);
    y0 = min(max(y0, 0), H - 1);
    y1 = min(max(y1, 0), H - 1);

    // Weights from the CLIPPED coords (matches the reference exactly)
    const double wa = ((double)x1 - x) * ((double)y1 - y);
    const double wb = ((double)x1 - x) * (y - (double)y0);
    const double wc = (x - (double)x0) * ((double)y1 - y);
    const double wd = (x - (double)x0) * (y - (double)y0);

    const int base = b << 18;
    const int pa = ((base | (y0 << 9)) | x0) << 1;   // f32x4 index, 2 per pixel
    const int pb = ((base | (y1 << 9)) | x0) << 1;
    const int pc = ((base | (y0 << 9)) | x1) << 1;
    const int pd = ((base | (y1 << 9)) | x1) << 1;

    // Issue all 8 gathers up front (MLP); compiler schedules waits late.
    const f32x4 A0 = X4[pa],     B0 = X4[pb],     C0 = X4[pc],     D0 = X4[pd];
    const f32x4 A1 = X4[pa + 1], B1 = X4[pb + 1], C1 = X4[pc + 1], D1 = X4[pd + 1];

    f32x4 o0, o1;
    #pragma unroll
    for (int j = 0; j < 4; ++j) {
        o0[j] = (float)(((wa * (double)A0[j] + wb * (double)B0[j]) + wc * (double)C0[j]) + wd * (double)D0[j]);
        o1[j] = (float)(((wa * (double)A1[j] + wb * (double)B1[j]) + wc * (double)C1[j]) + wd * (double)D1[j]);
    }

    // Nontemporal: output is write-once, don't evict the gather working set.
    __builtin_nontemporal_store(o0, &out4[(idx << 1) + 0]);
    __builtin_nontemporal_store(o1, &out4[(idx << 1) + 1]);
}

extern "C" void kernel_launch(void* const* d_in, const int* in_sizes, int n_in,
                              void* d_out, int out_size, void* d_ws, size_t ws_size,
                              hipStream_t stream) {
    const f32x4* X4    = (const f32x4*)d_in[0];
    const float* theta = (const float*)d_in[1];
    f32x4*       out4  = (f32x4*)d_out;

    const int total_threads = B * HW;               // 8,388,608 (one per pixel)
    const int blocks = total_threads / 256;         // 32768, exact

    stn_bilinear_kernel<<<blocks, 256, 0, stream>>>(X4, theta, out4);
}

// Round 5
// 92.220 us; speedup vs baseline: 1.3232x; 1.1633x over previous
//
#include <hip/hip_runtime.h>

// Fixed problem geometry from setup_inputs(): X (32,512,512,8) f32, theta (32,6) f32
constexpr int B = 32;
constexpr int H = 512;
constexpr int W = 512;
constexpr int HW = H * W;          // 262144 = 2^18
constexpr int NXCD = 8;

// Native vector type: __builtin_nontemporal_store requires scalar/ext-vector.
typedef float f32x4 __attribute__((ext_vector_type(4)));

// One thread per output pixel; each 256-thread block covers a 64x4 pixel TILE
// (4 waves = 4 adjacent output rows). Adjacent rows share bilinear source rows
// (y0/y1 overlap), and running them concurrently on one CU makes that sharing
// an L1 hit instead of an L2/L3 round-trip (round-4 counters: input is
// L3-resident, reads were ~1.07 GB logical vs 268 MB ideal -> y-overlap was
// the uncaptured 2x).
//
// Coordinate math in f64, numpy-exact (border discontinuities at the clip
// lines need f64 to match the numpy reference's floor/clip decisions).
__global__ __launch_bounds__(256) void stn_bilinear_kernel(
    const f32x4* __restrict__ X4,      // X viewed as f32x4: 2 per pixel
    const float* __restrict__ theta,   // (B,6)
    f32x4*       __restrict__ out4)    // same layout as X4
{
    // Grid: 32 images x 128 tile-rows x 8 tile-cols = 32768 blocks.
    // XCD-aware bijective swizzle: contiguous chunks of 4096 blocks per XCD
    // (= 4 consecutive images per XCD L2).
    const int nblk = 32768;
    const int cpx  = nblk / NXCD;                  // 4096
    const int bid  = (int)blockIdx.x;
    const int swz  = (bid % NXCD) * cpx + bid / NXCD;

    const int b    = swz >> 10;                    // / (8*128)
    const int rem  = swz & 1023;
    const int ty   = rem >> 3;                     // tile row 0..127
    const int tx   = rem & 7;                      // tile col 0..7

    const int tid  = (int)threadIdx.x;
    const int h    = (ty << 2) | (tid >> 6);       // 4 rows per tile
    const int w    = (tx << 6) | (tid & 63);       // 64 px per row

    const float* t = theta + b * 6;                // block-uniform
    const double t0 = (double)t[0], t1 = (double)t[1], t2 = (double)t[2];
    const double t3 = (double)t[3], t4 = (double)t[4], t5 = (double)t[5];

    // numpy linspace(-1,1,512) f64: i*delta + start, endpoint forced to stop
    const double step = 2.0 / 511.0;
    const double xg = (w == W - 1) ? 1.0 : (double)w * step - 1.0;
    const double yg = (h == H - 1) ? 1.0 : (double)h * step - 1.0;

    const double xt = (t0 * xg + t1 * yg) + t2;
    const double yt = (t3 * xg + t4 * yg) + t5;

    const double x = (0.5 * (xt + 1.0)) * (double)W;
    const double y = (0.5 * (yt + 1.0)) * (double)H;

    int x0 = (int)floor(x);
    int y0 = (int)floor(y);
    int x1 = x0 + 1;
    int y1 = y0 + 1;
    x0 = min(max(x0, 0), W - 1);
    x1 = min(max(x1, 0), W - 1);
    y0 = min(max(y0, 0), H - 1);
    y1 = min(max(y1, 0), H - 1);

    // Weights from the CLIPPED coords (matches the reference exactly)
    const double wa = ((double)x1 - x) * ((double)y1 - y);
    const double wb = ((double)x1 - x) * (y - (double)y0);
    const double wc = (x - (double)x0) * ((double)y1 - y);
    const double wd = (x - (double)x0) * (y - (double)y0);

    const int base = b << 18;
    const int pa = ((base | (y0 << 9)) | x0) << 1;   // f32x4 index, 2 per pixel
    const int pb = ((base | (y1 << 9)) | x0) << 1;
    const int pc = ((base | (y0 << 9)) | x1) << 1;
    const int pd = ((base | (y1 << 9)) | x1) << 1;

    // Issue all 8 gathers up front (MLP); compiler schedules waits late.
    const f32x4 A0 = X4[pa],     B0 = X4[pb],     C0 = X4[pc],     D0 = X4[pd];
    const f32x4 A1 = X4[pa + 1], B1 = X4[pb + 1], C1 = X4[pc + 1], D1 = X4[pd + 1];

    f32x4 o0, o1;
    #pragma unroll
    for (int j = 0; j < 4; ++j) {
        o0[j] = (float)(((wa * (double)A0[j] + wb * (double)B0[j]) + wc * (double)C0[j]) + wd * (double)D0[j]);
        o1[j] = (float)(((wa * (double)A1[j] + wb * (double)B1[j]) + wc * (double)C1[j]) + wd * (double)D1[j]);
    }

    // Nontemporal: output is write-once, keep L2/L3 for the gather reuse.
    const int oidx = ((base | (h << 9)) | w) << 1;
    __builtin_nontemporal_store(o0, &out4[oidx + 0]);
    __builtin_nontemporal_store(o1, &out4[oidx + 1]);
}

extern "C" void kernel_launch(void* const* d_in, const int* in_sizes, int n_in,
                              void* d_out, int out_size, void* d_ws, size_t ws_size,
                              hipStream_t stream) {
    const f32x4* X4    = (const f32x4*)d_in[0];
    const float* theta = (const float*)d_in[1];
    f32x4*       out4  = (f32x4*)d_out;

    stn_bilinear_kernel<<<32768, 256, 0, stream>>>(X4, theta, out4);
}